// Round 13
// baseline (96.218 us; speedup 1.0000x reference)
//
#include <hip/hip_runtime.h>
#include <math.h>

// Problem constants
#define BB    16
#define DIMM  1024
#define TN    2048
#define NBINS 625

typedef float f4 __attribute__((ext_vector_type(4)));  // for nontemporal store

// Output layout (floats, concatenated in reference return order)
//   zero: 4 | feat_t: B*DIM*T | perplexity: 4 | ind_t: B*4*T
static constexpr size_t OUT_ZERO = 0;
static constexpr size_t OUT_FEAT = 4;
static constexpr size_t OUT_PERP = 4 + (size_t)BB * DIMM * TN;
static constexpr size_t OUT_IND  = OUT_PERP + 4;

// Workspace: qbuf4 [g][b][t] (1 MB) @ 0 ; counts 4*625 floats @ 1 MB;
//            arrival counters 4 ints @ 1 MB + 16 KB.

// ---------------------------------------------------------------------------
// K1: projection + FSQ. Block = (b, 128-t tile), 512 threads (8 waves).
// f64 accumulation/FSQ chain (bit-matches np ref, proven R1-R12).
// ~25us, ~5.2 TB/s read; FROZEN since R7.
// Block (0,0) additionally zeroes counts + arrival counters + zero output
// (completes before K2's atomics: separate dispatch on the same stream).
// ---------------------------------------------------------------------------
__global__ __launch_bounds__(512) void gfsq_k1(const float* __restrict__ x,
                                               const float* __restrict__ w_in,
                                               const float* __restrict__ b_in,
                                               float4* __restrict__ qbuf4,
                                               float* __restrict__ counts,
                                               int* __restrict__ arrival,
                                               float* __restrict__ out) {
  const int tt   = blockIdx.x;   // 0..15 (128-t tile)
  const int b    = blockIdx.y;   // 0..15
  const int tid  = threadIdx.x;
  const int w    = tid >> 6;     // wave 0..7
  const int lane = tid & 63;

  if (tt == 0 && b == 0) {
    for (int i = tid; i < 4 * NBINS; i += 512) counts[i] = 0.0f;
    if (tid < 4) arrival[tid] = 0;
    if (tid < 4) out[OUT_ZERO + tid] = 0.0f;
  }

  __shared__ float4 wl4[1024];          // 16 KB: row -> (c0,c1,c2,c3)
  __shared__ double sacc[8][4][128];    // 32 KB: [wave][c][t_local]

  for (int i = tid; i < 1024; i += 512) {
    const int g = i >> 9, d = i & 511;
    const float* wp = w_in + g * 2048 + d;
    wl4[i] = make_float4(wp[0], wp[512], wp[1024], wp[1536]);
  }
  __syncthreads();

  // read phase: wave w owns rows [w*128, +128); lane covers t-pair
  const float* xp = x + ((size_t)b * DIMM + (size_t)w * 128) * TN
                      + tt * 128 + lane * 2;
  double a00 = 0.0, a01 = 0.0, a10 = 0.0, a11 = 0.0;
  double a20 = 0.0, a21 = 0.0, a30 = 0.0, a31 = 0.0;
  #pragma unroll 8
  for (int r = 0; r < 128; ++r) {
    const float2 xv = *(const float2*)(xp + (size_t)r * TN);
    const float4 wv = wl4[w * 128 + r];
    a00 += (double)wv.x * (double)xv.x;  a01 += (double)wv.x * (double)xv.y;
    a10 += (double)wv.y * (double)xv.x;  a11 += (double)wv.y * (double)xv.y;
    a20 += (double)wv.z * (double)xv.x;  a21 += (double)wv.z * (double)xv.y;
    a30 += (double)wv.w * (double)xv.x;  a31 += (double)wv.w * (double)xv.y;
  }
  sacc[w][0][lane * 2] = a00;  sacc[w][0][lane * 2 + 1] = a01;
  sacc[w][1][lane * 2] = a10;  sacc[w][1][lane * 2 + 1] = a11;
  sacc[w][2][lane * 2] = a20;  sacc[w][2][lane * 2 + 1] = a21;
  sacc[w][3][lane * 2] = a30;  sacc[w][3][lane * 2 + 1] = a31;
  __syncthreads();

  // reduce + FSQ: thread -> (t_local, g); waves 4g..4g+3 hold g's partials
  if (tid < 256) {
    const int tl = tid >> 1;      // 0..127
    const int g  = tid & 1;
    const int t  = tt * 128 + tl;
    const double half_l = (5.0 - 1.0) * (1.0 + 1e-3) / 2.0;  // match np expr
    const int basis[4] = {1, 5, 25, 125};
    float q[4];
    int idx0 = 0, idx1 = 0;
    #pragma unroll
    for (int c = 0; c < 4; ++c) {
      double z = (double)b_in[g * 4 + c]
               + sacc[4 * g + 0][c][tl] + sacc[4 * g + 1][c][tl]
               + sacc[4 * g + 2][c][tl] + sacc[4 * g + 3][c][tl];
      double n0 = rint(tanh(z) * half_l);          // step 0, s=1
      double r1 = z - 0.5 * n0;
      double n1 = rint(tanh(4.0 * r1) * half_l);   // step 1, s=0.25
      q[c] = (float)(0.5 * n0 + 0.125 * n1);       // exact in f32
      idx0 += ((int)n0 + 2) * basis[c];
      idx1 += ((int)n1 + 2) * basis[c];
    }
    out[OUT_IND + ((size_t)b * 4 + g * 2 + 0) * TN + t] = (float)idx0;
    out[OUT_IND + ((size_t)b * 4 + g * 2 + 1) * TN + t] = (float)idx1;
    qbuf4[(size_t)g * BB * TN + (size_t)b * TN + t] =
        make_float4(q[0], q[1], q[2], q[3]);
  }
}

// ---------------------------------------------------------------------------
// K2: feat out-projection (dc<64): R11/R12 compact geometry (16 consecutive
// dims x all 2048 t = one contiguous 128KB window/block) but with
// NONTEMPORAL stores: feat is never re-read, so skipping L2 write-allocate
// frees the cache for qbuf/ind (single-variable change vs R12).
// dc 64..67: parallel histogram (16 slice-blocks per row j, per-wave LDS
// hists, exact float merges). The LAST-arriving slice block per j (device
// atomic + threadfence) computes perplexity inline — K3 eliminated.
// ---------------------------------------------------------------------------
__global__ __launch_bounds__(512) void gfsq_k2(const float4* __restrict__ qbuf4,
                                               const float* __restrict__ w_out,
                                               const float* __restrict__ b_out,
                                               float* __restrict__ counts,
                                               int* __restrict__ arrival,
                                               float* __restrict__ out) {
  const int dc  = blockIdx.x;   // 0..63 feat (16 dims each); 64..67 hist
  const int b   = blockIdx.y;   // feat: batch; hist: slice 0..15
  const int tid = threadIdx.x;

  if (dc >= 64) {
    const int j = dc - 64;      // codebook row
    const int w = tid >> 6;
    __shared__ float  whist[8][NBINS];   // 20 KB, per-wave
    __shared__ double red[512];          // 4 KB
    __shared__ int    lastflag;
    for (int i = tid; i < 8 * NBINS; i += 512) ((float*)whist)[i] = 0.0f;
    __syncthreads();
    // slice b covers elements [b*2048, +2048) of the 32768 (b2,t) pairs
    const int e0 = b * 2048 + tid * 4;
    const int b2 = e0 >> 11;
    const int t0 = e0 & 2047;
    const float4 iv =
        *(const float4*)&out[OUT_IND + ((size_t)b2 * 4 + j) * TN + t0];
    atomicAdd(&whist[w][(int)iv.x], 1.0f);
    atomicAdd(&whist[w][(int)iv.y], 1.0f);
    atomicAdd(&whist[w][(int)iv.z], 1.0f);
    atomicAdd(&whist[w][(int)iv.w], 1.0f);
    __syncthreads();
    for (int i = tid; i < NBINS; i += 512) {
      const float s = whist[0][i] + whist[1][i] + whist[2][i] + whist[3][i]
                    + whist[4][i] + whist[5][i] + whist[6][i] + whist[7][i];
      if (s != 0.0f) atomicAdd(&counts[j * NBINS + i], s);
    }
    // release: make our count contributions visible, then arrive
    __threadfence();
    if (tid == 0) lastflag = (atomicAdd(&arrival[j], 1) == 15);
    __syncthreads();
    if (!lastflag) return;
    __threadfence();  // acquire: other blocks' merges now visible
    // perplexity for row j (f64 chain identical to proven K3; counts are
    // exact integers -> deterministic). volatile loads bypass L1.
    const volatile float* cv = counts + j * NBINS;
    double s = 0.0;
    for (int i = tid; i < NBINS; i += 512) s += (double)cv[i];
    red[tid] = s;
    __syncthreads();
    for (int off = 256; off; off >>= 1) {
      if (tid < off) red[tid] += red[tid + off];
      __syncthreads();
    }
    const double tot = red[0] / 32768.0;  // == 1.0 exactly
    __syncthreads();
    double h = 0.0;
    for (int i = tid; i < NBINS; i += 512) {
      double e  = (double)cv[i] / 32768.0;
      double e2 = e / (tot + 1e-5);
      h += e2 * log(e2 + 1e-5);
    }
    red[tid] = h;
    __syncthreads();
    for (int off = 256; off; off >>= 1) {
      if (tid < off) red[tid] += red[tid + off];
      __syncthreads();
    }
    if (tid == 0) out[OUT_PERP + j] = (float)exp(-red[0]);
    return;
  }

  const int g = dc >> 5;  // dims [dc*16, +16); g=0 for dc<32

  __shared__ float4 wrow[16];
  __shared__ float  brow[16];
  if (tid < 16) {
    wrow[tid] = ((const float4*)w_out)[dc * 16 + tid];  // w_out flat: dim*4+c
    brow[tid] = b_out[dc * 16 + tid];
  }
  __syncthreads();

  const int t = tid * 4;   // 512 threads x 4 t = full 2048
  const float4* qp = qbuf4 + (size_t)g * BB * TN + (size_t)b * TN + t;
  const float4 q0 = qp[0], q1 = qp[1], q2 = qp[2], q3 = qp[3];

  float* op = out + OUT_FEAT + ((size_t)b * DIMM + (size_t)dc * 16) * TN + t;
  #pragma unroll
  for (int d = 0; d < 16; ++d) {
    const float4 wv = wrow[d];
    const float  bb = brow[d];
    f4 r;
    r.x = bb + wv.x * q0.x + wv.y * q0.y + wv.z * q0.z + wv.w * q0.w;
    r.y = bb + wv.x * q1.x + wv.y * q1.y + wv.z * q1.z + wv.w * q1.w;
    r.z = bb + wv.x * q2.x + wv.y * q2.y + wv.z * q2.z + wv.w * q2.w;
    r.w = bb + wv.x * q3.x + wv.y * q3.y + wv.z * q3.z + wv.w * q3.w;
    __builtin_nontemporal_store(r, (f4*)(op + (size_t)d * TN));
  }
}

// ---------------------------------------------------------------------------
extern "C" void kernel_launch(void* const* d_in, const int* in_sizes, int n_in,
                              void* d_out, int out_size, void* d_ws, size_t ws_size,
                              hipStream_t stream) {
  (void)in_sizes; (void)n_in; (void)out_size; (void)ws_size;

  const float* x     = (const float*)d_in[0];
  const float* w_in  = (const float*)d_in[1];
  const float* b_in  = (const float*)d_in[2];
  const float* w_out = (const float*)d_in[3];
  const float* b_out = (const float*)d_in[4];
  float*  out     = (float*)d_out;
  float4* qbuf4   = (float4*)d_ws;                        // 1 MB, [g][b][t]
  float*  counts  = (float*)((char*)d_ws + (1 << 20));    // 2500 floats
  int*    arrival = (int*)((char*)d_ws + (1 << 20) + 16384);  // 4 ints

  gfsq_k1<<<dim3(16, 16), 512, 0, stream>>>(x, w_in, b_in, qbuf4, counts,
                                            arrival, out);
  gfsq_k2<<<dim3(68, 16), 512, 0, stream>>>(qbuf4, w_out, b_out, counts,
                                            arrival, out);
}

// Round 14
// 78.768 us; speedup vs baseline: 1.2215x; 1.2215x over previous
//
#include <hip/hip_runtime.h>
#include <math.h>

// Problem constants
#define BB    16
#define DIMM  1024
#define TN    2048
#define NBINS 625

// Output layout (floats, concatenated in reference return order)
//   zero: 4 | feat_t: B*DIM*T | perplexity: 4 | ind_t: B*4*T
static constexpr size_t OUT_ZERO = 0;
static constexpr size_t OUT_FEAT = 4;
static constexpr size_t OUT_PERP = 4 + (size_t)BB * DIMM * TN;
static constexpr size_t OUT_IND  = OUT_PERP + 4;

// Workspace: qbuf4 [g][b][t] (1 MB) @ 0 ; counts 4*625 floats @ 1 MB;
//            arrival counters 4 ints @ 1 MB + 16 KB.

// ---------------------------------------------------------------------------
// K1: projection + FSQ. Block = (b, 128-t tile), 512 threads (8 waves).
// f64 accumulation/FSQ chain (bit-matches np ref, proven R1-R13).
// ~25us, ~5.2 TB/s read; FROZEN since R7.
// Block (0,0) additionally zeroes counts + arrival counters + zero output
// (completes before K2's atomics: separate dispatch on the same stream).
// ---------------------------------------------------------------------------
__global__ __launch_bounds__(512) void gfsq_k1(const float* __restrict__ x,
                                               const float* __restrict__ w_in,
                                               const float* __restrict__ b_in,
                                               float4* __restrict__ qbuf4,
                                               float* __restrict__ counts,
                                               int* __restrict__ arrival,
                                               float* __restrict__ out) {
  const int tt   = blockIdx.x;   // 0..15 (128-t tile)
  const int b    = blockIdx.y;   // 0..15
  const int tid  = threadIdx.x;
  const int w    = tid >> 6;     // wave 0..7
  const int lane = tid & 63;

  if (tt == 0 && b == 0) {
    for (int i = tid; i < 4 * NBINS; i += 512) counts[i] = 0.0f;
    if (tid < 4) arrival[tid] = 0;
    if (tid < 4) out[OUT_ZERO + tid] = 0.0f;
  }

  __shared__ float4 wl4[1024];          // 16 KB: row -> (c0,c1,c2,c3)
  __shared__ double sacc[8][4][128];    // 32 KB: [wave][c][t_local]

  for (int i = tid; i < 1024; i += 512) {
    const int g = i >> 9, d = i & 511;
    const float* wp = w_in + g * 2048 + d;
    wl4[i] = make_float4(wp[0], wp[512], wp[1024], wp[1536]);
  }
  __syncthreads();

  // read phase: wave w owns rows [w*128, +128); lane covers t-pair
  const float* xp = x + ((size_t)b * DIMM + (size_t)w * 128) * TN
                      + tt * 128 + lane * 2;
  double a00 = 0.0, a01 = 0.0, a10 = 0.0, a11 = 0.0;
  double a20 = 0.0, a21 = 0.0, a30 = 0.0, a31 = 0.0;
  #pragma unroll 8
  for (int r = 0; r < 128; ++r) {
    const float2 xv = *(const float2*)(xp + (size_t)r * TN);
    const float4 wv = wl4[w * 128 + r];
    a00 += (double)wv.x * (double)xv.x;  a01 += (double)wv.x * (double)xv.y;
    a10 += (double)wv.y * (double)xv.x;  a11 += (double)wv.y * (double)xv.y;
    a20 += (double)wv.z * (double)xv.x;  a21 += (double)wv.z * (double)xv.y;
    a30 += (double)wv.w * (double)xv.x;  a31 += (double)wv.w * (double)xv.y;
  }
  sacc[w][0][lane * 2] = a00;  sacc[w][0][lane * 2 + 1] = a01;
  sacc[w][1][lane * 2] = a10;  sacc[w][1][lane * 2 + 1] = a11;
  sacc[w][2][lane * 2] = a20;  sacc[w][2][lane * 2 + 1] = a21;
  sacc[w][3][lane * 2] = a30;  sacc[w][3][lane * 2 + 1] = a31;
  __syncthreads();

  // reduce + FSQ: thread -> (t_local, g); waves 4g..4g+3 hold g's partials
  if (tid < 256) {
    const int tl = tid >> 1;      // 0..127
    const int g  = tid & 1;
    const int t  = tt * 128 + tl;
    const double half_l = (5.0 - 1.0) * (1.0 + 1e-3) / 2.0;  // match np expr
    const int basis[4] = {1, 5, 25, 125};
    float q[4];
    int idx0 = 0, idx1 = 0;
    #pragma unroll
    for (int c = 0; c < 4; ++c) {
      double z = (double)b_in[g * 4 + c]
               + sacc[4 * g + 0][c][tl] + sacc[4 * g + 1][c][tl]
               + sacc[4 * g + 2][c][tl] + sacc[4 * g + 3][c][tl];
      double n0 = rint(tanh(z) * half_l);          // step 0, s=1
      double r1 = z - 0.5 * n0;
      double n1 = rint(tanh(4.0 * r1) * half_l);   // step 1, s=0.25
      q[c] = (float)(0.5 * n0 + 0.125 * n1);       // exact in f32
      idx0 += ((int)n0 + 2) * basis[c];
      idx1 += ((int)n1 + 2) * basis[c];
    }
    out[OUT_IND + ((size_t)b * 4 + g * 2 + 0) * TN + t] = (float)idx0;
    out[OUT_IND + ((size_t)b * 4 + g * 2 + 1) * TN + t] = (float)idx1;
    qbuf4[(size_t)g * BB * TN + (size_t)b * TN + t] =
        make_float4(q[0], q[1], q[2], q[3]);
  }
}

// ---------------------------------------------------------------------------
// K2: feat out-projection (dc<64): R12's proven geometry and REGULAR stores
// (nt-store refuted twice: R10 +10us, R13 +39us — L2 write-allocate is the
// fast path for streaming stores on MI355X). 16 consecutive dims x all
// 2048 t = one contiguous 128KB window per block; 1024 blocks x 512 th.
// dc 64..67: parallel histogram (16 slice-blocks per row j, per-wave LDS
// hists, exact float merges). The LAST-arriving slice block per j (device
// atomic + threadfence) computes perplexity inline — K3 node eliminated.
// ---------------------------------------------------------------------------
__global__ __launch_bounds__(512) void gfsq_k2(const float4* __restrict__ qbuf4,
                                               const float* __restrict__ w_out,
                                               const float* __restrict__ b_out,
                                               float* __restrict__ counts,
                                               int* __restrict__ arrival,
                                               float* __restrict__ out) {
  const int dc  = blockIdx.x;   // 0..63 feat (16 dims each); 64..67 hist
  const int b   = blockIdx.y;   // feat: batch; hist: slice 0..15
  const int tid = threadIdx.x;

  if (dc >= 64) {
    const int j = dc - 64;      // codebook row
    const int w = tid >> 6;
    __shared__ float  whist[8][NBINS];   // 20 KB, per-wave
    __shared__ double red[512];          // 4 KB
    __shared__ int    lastflag;
    for (int i = tid; i < 8 * NBINS; i += 512) ((float*)whist)[i] = 0.0f;
    __syncthreads();
    // slice b covers elements [b*2048, +2048) of the 32768 (b2,t) pairs
    const int e0 = b * 2048 + tid * 4;
    const int b2 = e0 >> 11;
    const int t0 = e0 & 2047;
    const float4 iv =
        *(const float4*)&out[OUT_IND + ((size_t)b2 * 4 + j) * TN + t0];
    atomicAdd(&whist[w][(int)iv.x], 1.0f);
    atomicAdd(&whist[w][(int)iv.y], 1.0f);
    atomicAdd(&whist[w][(int)iv.z], 1.0f);
    atomicAdd(&whist[w][(int)iv.w], 1.0f);
    __syncthreads();
    for (int i = tid; i < NBINS; i += 512) {
      const float s = whist[0][i] + whist[1][i] + whist[2][i] + whist[3][i]
                    + whist[4][i] + whist[5][i] + whist[6][i] + whist[7][i];
      if (s != 0.0f) atomicAdd(&counts[j * NBINS + i], s);
    }
    // release: make our count contributions visible, then arrive
    __threadfence();
    if (tid == 0) lastflag = (atomicAdd(&arrival[j], 1) == 15);
    __syncthreads();
    if (!lastflag) return;
    __threadfence();  // acquire: other blocks' merges now visible
    // perplexity for row j (f64 chain identical to proven K3; counts are
    // exact integers -> deterministic). volatile loads bypass caching.
    const volatile float* cv = counts + j * NBINS;
    double s = 0.0;
    for (int i = tid; i < NBINS; i += 512) s += (double)cv[i];
    red[tid] = s;
    __syncthreads();
    for (int off = 256; off; off >>= 1) {
      if (tid < off) red[tid] += red[tid + off];
      __syncthreads();
    }
    const double tot = red[0] / 32768.0;  // == 1.0 exactly
    __syncthreads();
    double h = 0.0;
    for (int i = tid; i < NBINS; i += 512) {
      double e  = (double)cv[i] / 32768.0;
      double e2 = e / (tot + 1e-5);
      h += e2 * log(e2 + 1e-5);
    }
    red[tid] = h;
    __syncthreads();
    for (int off = 256; off; off >>= 1) {
      if (tid < off) red[tid] += red[tid + off];
      __syncthreads();
    }
    if (tid == 0) out[OUT_PERP + j] = (float)exp(-red[0]);
    return;
  }

  const int g = dc >> 5;  // dims [dc*16, +16); g=0 for dc<32

  __shared__ float4 wrow[16];
  __shared__ float  brow[16];
  if (tid < 16) {
    wrow[tid] = ((const float4*)w_out)[dc * 16 + tid];  // w_out flat: dim*4+c
    brow[tid] = b_out[dc * 16 + tid];
  }
  __syncthreads();

  const int t = tid * 4;   // 512 threads x 4 t = full 2048
  const float4* qp = qbuf4 + (size_t)g * BB * TN + (size_t)b * TN + t;
  const float4 q0 = qp[0], q1 = qp[1], q2 = qp[2], q3 = qp[3];

  float* op = out + OUT_FEAT + ((size_t)b * DIMM + (size_t)dc * 16) * TN + t;
  #pragma unroll
  for (int d = 0; d < 16; ++d) {
    const float4 wv = wrow[d];
    const float  bb = brow[d];
    float4 r;
    r.x = bb + wv.x * q0.x + wv.y * q0.y + wv.z * q0.z + wv.w * q0.w;
    r.y = bb + wv.x * q1.x + wv.y * q1.y + wv.z * q1.z + wv.w * q1.w;
    r.z = bb + wv.x * q2.x + wv.y * q2.y + wv.z * q2.z + wv.w * q2.w;
    r.w = bb + wv.x * q3.x + wv.y * q3.y + wv.z * q3.z + wv.w * q3.w;
    *(float4*)(op + (size_t)d * TN) = r;
  }
}

// ---------------------------------------------------------------------------
extern "C" void kernel_launch(void* const* d_in, const int* in_sizes, int n_in,
                              void* d_out, int out_size, void* d_ws, size_t ws_size,
                              hipStream_t stream) {
  (void)in_sizes; (void)n_in; (void)out_size; (void)ws_size;

  const float* x     = (const float*)d_in[0];
  const float* w_in  = (const float*)d_in[1];
  const float* b_in  = (const float*)d_in[2];
  const float* w_out = (const float*)d_in[3];
  const float* b_out = (const float*)d_in[4];
  float*  out     = (float*)d_out;
  float4* qbuf4   = (float4*)d_ws;                        // 1 MB, [g][b][t]
  float*  counts  = (float*)((char*)d_ws + (1 << 20));    // 2500 floats
  int*    arrival = (int*)((char*)d_ws + (1 << 20) + 16384);  // 4 ints

  gfsq_k1<<<dim3(16, 16), 512, 0, stream>>>(x, w_in, b_in, qbuf4, counts,
                                            arrival, out);
  gfsq_k2<<<dim3(68, 16), 512, 0, stream>>>(qbuf4, w_out, b_out, counts,
                                            arrival, out);
}

// Round 15
// 57.209 us; speedup vs baseline: 1.6819x; 1.3768x over previous
//
#include <hip/hip_runtime.h>
#include <math.h>

// Problem constants
#define BB    16
#define DIMM  1024
#define TN    2048
#define NBINS 625

// Output layout (floats, concatenated in reference return order)
//   zero: 4 | feat_t: B*DIM*T | perplexity: 4 | ind_t: B*4*T
static constexpr size_t OUT_ZERO = 0;
static constexpr size_t OUT_FEAT = 4;
static constexpr size_t OUT_PERP = 4 + (size_t)BB * DIMM * TN;
static constexpr size_t OUT_IND  = OUT_PERP + 4;

// Workspace: qbuf4 [g][b][t] (1 MB) @ 0 ; counts 4*625 floats @ 1 MB.

// ---------------------------------------------------------------------------
// K1: projection + FSQ. Block = (b, 128-t tile), 512 threads (8 waves).
// f64 accumulation/FSQ chain (bit-matches np ref, proven R1-R14).
// ~25us, ~5.2 TB/s read; FROZEN since R7.
// Block (0,0) additionally zeroes the global counts buffer (completes before
// K2's atomics: separate dispatch on the same stream).
// ---------------------------------------------------------------------------
__global__ __launch_bounds__(512) void gfsq_k1(const float* __restrict__ x,
                                               const float* __restrict__ w_in,
                                               const float* __restrict__ b_in,
                                               float4* __restrict__ qbuf4,
                                               float* __restrict__ counts,
                                               float* __restrict__ out) {
  const int tt   = blockIdx.x;   // 0..15 (128-t tile)
  const int b    = blockIdx.y;   // 0..15
  const int tid  = threadIdx.x;
  const int w    = tid >> 6;     // wave 0..7
  const int lane = tid & 63;

  if (tt == 0 && b == 0) {
    for (int i = tid; i < 4 * NBINS; i += 512) counts[i] = 0.0f;
  }

  __shared__ float4 wl4[1024];          // 16 KB: row -> (c0,c1,c2,c3)
  __shared__ double sacc[8][4][128];    // 32 KB: [wave][c][t_local]

  for (int i = tid; i < 1024; i += 512) {
    const int g = i >> 9, d = i & 511;
    const float* wp = w_in + g * 2048 + d;
    wl4[i] = make_float4(wp[0], wp[512], wp[1024], wp[1536]);
  }
  __syncthreads();

  // read phase: wave w owns rows [w*128, +128); lane covers t-pair
  const float* xp = x + ((size_t)b * DIMM + (size_t)w * 128) * TN
                      + tt * 128 + lane * 2;
  double a00 = 0.0, a01 = 0.0, a10 = 0.0, a11 = 0.0;
  double a20 = 0.0, a21 = 0.0, a30 = 0.0, a31 = 0.0;
  #pragma unroll 8
  for (int r = 0; r < 128; ++r) {
    const float2 xv = *(const float2*)(xp + (size_t)r * TN);
    const float4 wv = wl4[w * 128 + r];
    a00 += (double)wv.x * (double)xv.x;  a01 += (double)wv.x * (double)xv.y;
    a10 += (double)wv.y * (double)xv.x;  a11 += (double)wv.y * (double)xv.y;
    a20 += (double)wv.z * (double)xv.x;  a21 += (double)wv.z * (double)xv.y;
    a30 += (double)wv.w * (double)xv.x;  a31 += (double)wv.w * (double)xv.y;
  }
  sacc[w][0][lane * 2] = a00;  sacc[w][0][lane * 2 + 1] = a01;
  sacc[w][1][lane * 2] = a10;  sacc[w][1][lane * 2 + 1] = a11;
  sacc[w][2][lane * 2] = a20;  sacc[w][2][lane * 2 + 1] = a21;
  sacc[w][3][lane * 2] = a30;  sacc[w][3][lane * 2 + 1] = a31;
  __syncthreads();

  // reduce + FSQ: thread -> (t_local, g); waves 4g..4g+3 hold g's partials
  if (tid < 256) {
    const int tl = tid >> 1;      // 0..127
    const int g  = tid & 1;
    const int t  = tt * 128 + tl;
    const double half_l = (5.0 - 1.0) * (1.0 + 1e-3) / 2.0;  // match np expr
    const int basis[4] = {1, 5, 25, 125};
    float q[4];
    int idx0 = 0, idx1 = 0;
    #pragma unroll
    for (int c = 0; c < 4; ++c) {
      double z = (double)b_in[g * 4 + c]
               + sacc[4 * g + 0][c][tl] + sacc[4 * g + 1][c][tl]
               + sacc[4 * g + 2][c][tl] + sacc[4 * g + 3][c][tl];
      double n0 = rint(tanh(z) * half_l);          // step 0, s=1
      double r1 = z - 0.5 * n0;
      double n1 = rint(tanh(4.0 * r1) * half_l);   // step 1, s=0.25
      q[c] = (float)(0.5 * n0 + 0.125 * n1);       // exact in f32
      idx0 += ((int)n0 + 2) * basis[c];
      idx1 += ((int)n1 + 2) * basis[c];
    }
    out[OUT_IND + ((size_t)b * 4 + g * 2 + 0) * TN + t] = (float)idx0;
    out[OUT_IND + ((size_t)b * 4 + g * 2 + 1) * TN + t] = (float)idx1;
    qbuf4[(size_t)g * BB * TN + (size_t)b * TN + t] =
        make_float4(q[0], q[1], q[2], q[3]);
  }
}

// ---------------------------------------------------------------------------
// K2: feat out-projection (dc<64): compact geometry (16 consecutive dims x
// all 2048 t = one contiguous 128KB window per block) with REGULAR stores
// (nt refuted R10/R13; device fences in-stream refuted R14).
// dc 64..67: parallel histogram (16 slice-blocks per row j, per-wave LDS
// hists, exact float merges into global counts — integer-valued floats add
// exactly in any order => deterministic). No fences here (R14 lesson).
// ---------------------------------------------------------------------------
__global__ __launch_bounds__(512) void gfsq_k2(const float4* __restrict__ qbuf4,
                                               const float* __restrict__ w_out,
                                               const float* __restrict__ b_out,
                                               float* __restrict__ counts,
                                               float* __restrict__ out) {
  const int dc  = blockIdx.x;   // 0..63 feat (16 dims each); 64..67 hist
  const int b   = blockIdx.y;   // feat: batch; hist: slice 0..15
  const int tid = threadIdx.x;

  if (dc >= 64) {
    const int j = dc - 64;      // codebook row
    const int w = tid >> 6;
    __shared__ float whist[8][NBINS];   // 20 KB, per-wave
    for (int i = tid; i < 8 * NBINS; i += 512) ((float*)whist)[i] = 0.0f;
    __syncthreads();
    // slice b covers elements [b*2048, +2048) of the 32768 (b2,t) pairs
    const int e0 = b * 2048 + tid * 4;
    const int b2 = e0 >> 11;
    const int t0 = e0 & 2047;
    const float4 iv =
        *(const float4*)&out[OUT_IND + ((size_t)b2 * 4 + j) * TN + t0];
    atomicAdd(&whist[w][(int)iv.x], 1.0f);
    atomicAdd(&whist[w][(int)iv.y], 1.0f);
    atomicAdd(&whist[w][(int)iv.z], 1.0f);
    atomicAdd(&whist[w][(int)iv.w], 1.0f);
    __syncthreads();
    for (int i = tid; i < NBINS; i += 512) {
      const float s = whist[0][i] + whist[1][i] + whist[2][i] + whist[3][i]
                    + whist[4][i] + whist[5][i] + whist[6][i] + whist[7][i];
      if (s != 0.0f) atomicAdd(&counts[j * NBINS + i], s);
    }
    return;
  }

  const int g = dc >> 5;  // dims [dc*16, +16); g=0 for dc<32

  __shared__ float4 wrow[16];
  __shared__ float  brow[16];
  if (tid < 16) {
    wrow[tid] = ((const float4*)w_out)[dc * 16 + tid];  // w_out flat: dim*4+c
    brow[tid] = b_out[dc * 16 + tid];
  }
  __syncthreads();

  const int t = tid * 4;   // 512 threads x 4 t = full 2048
  const float4* qp = qbuf4 + (size_t)g * BB * TN + (size_t)b * TN + t;
  const float4 q0 = qp[0], q1 = qp[1], q2 = qp[2], q3 = qp[3];

  float* op = out + OUT_FEAT + ((size_t)b * DIMM + (size_t)dc * 16) * TN + t;
  #pragma unroll
  for (int d = 0; d < 16; ++d) {
    const float4 wv = wrow[d];
    const float  bb = brow[d];
    float4 r;
    r.x = bb + wv.x * q0.x + wv.y * q0.y + wv.z * q0.z + wv.w * q0.w;
    r.y = bb + wv.x * q1.x + wv.y * q1.y + wv.z * q1.z + wv.w * q1.w;
    r.z = bb + wv.x * q2.x + wv.y * q2.y + wv.z * q2.z + wv.w * q2.w;
    r.w = bb + wv.x * q3.x + wv.y * q3.y + wv.z * q3.z + wv.w * q3.w;
    *(float4*)(op + (size_t)d * TN) = r;
  }
}

// ---------------------------------------------------------------------------
// K3: perplexity from final counts (f64 chain; counts are exact integers,
// deterministic). 4 blocks, ~2us — node overhead measured tiny at R12.
// ---------------------------------------------------------------------------
__global__ __launch_bounds__(256) void gfsq_k3(const float* __restrict__ counts,
                                               float* __restrict__ out) {
  const int j   = blockIdx.x;   // codebook row 0..3
  const int tid = threadIdx.x;

  __shared__ double red[256];
  double s = 0.0;
  for (int i = tid; i < NBINS; i += 256) s += (double)counts[j * NBINS + i];
  red[tid] = s;
  __syncthreads();
  for (int off = 128; off; off >>= 1) {
    if (tid < off) red[tid] += red[tid + off];
    __syncthreads();
  }
  const double tot = red[0] / 32768.0;  // == 1.0 exactly
  __syncthreads();

  double h = 0.0;
  for (int i = tid; i < NBINS; i += 256) {
    double e  = (double)counts[j * NBINS + i] / 32768.0;
    double e2 = e / (tot + 1e-5);
    h += e2 * log(e2 + 1e-5);
  }
  red[tid] = h;
  __syncthreads();
  for (int off = 128; off; off >>= 1) {
    if (tid < off) red[tid] += red[tid + off];
    __syncthreads();
  }
  if (tid == 0) out[OUT_PERP + j] = (float)exp(-red[0]);
  if (j == 0 && tid < 4) out[OUT_ZERO + tid] = 0.0f;
}

// ---------------------------------------------------------------------------
extern "C" void kernel_launch(void* const* d_in, const int* in_sizes, int n_in,
                              void* d_out, int out_size, void* d_ws, size_t ws_size,
                              hipStream_t stream) {
  (void)in_sizes; (void)n_in; (void)out_size; (void)ws_size;

  const float* x     = (const float*)d_in[0];
  const float* w_in  = (const float*)d_in[1];
  const float* b_in  = (const float*)d_in[2];
  const float* w_out = (const float*)d_in[3];
  const float* b_out = (const float*)d_in[4];
  float*  out    = (float*)d_out;
  float4* qbuf4  = (float4*)d_ws;                       // 1 MB, [g][b][t]
  float*  counts = (float*)((char*)d_ws + (1 << 20));   // 2500 floats

  gfsq_k1<<<dim3(16, 16), 512, 0, stream>>>(x, w_in, b_in, qbuf4, counts, out);
  gfsq_k2<<<dim3(68, 16), 512, 0, stream>>>(qbuf4, w_out, b_out, counts, out);
  gfsq_k3<<<4, 256, 0, stream>>>(counts, out);
}